// Round 1
// baseline (426.581 us; speedup 1.0000x reference)
//
#include <hip/hip_runtime.h>

// Correlation layer: out[b, di*9+dj, h, w] = (1/64) * sum_c x1[b,c,h,w] * x2p[b,c,h+di,w+dj]
// x2p = x2 zero-padded by 4 on each spatial side. di,dj in [0,9).
//
// Shapes fixed by the problem: B=8, C=64, H=W=192.
//
// Block: 576 threads = 9 waves. tid -> (g = tid&63 pixel-group, di = tid>>6).
//   di is wave-uniform (wave w handles displacement row di=w).
//   group g -> (gh = g>>3 in [0,8), gw4 = (g&7)*4): 4 consecutive w-pixels, one row.
// Each thread accumulates acc[9 dj][4 px] = 36 VGPRs for its fixed di.
// Channels staged through LDS in chunks of 16 (x1 tile 16KB + x2 halo tile 40KB = 56KB).
// Per channel: 4x ds_read_b128 feed 36 v_fmac_f32 (window slide over dj reuses x2 reads).

constexpr int MAXD = 4;
constexpr int OD   = 9;    // 2*MAXD+1
constexpr int ND   = 81;   // OD*OD
constexpr int TB_W = 32;   // tile width (pixels)
constexpr int TB_H = 8;    // tile height
constexpr int TWp  = 4;    // pixels per thread along w
constexpr int CK   = 16;   // channels per LDS chunk
constexpr int X2W  = TB_W + 2 * MAXD;  // 40
constexpr int X2H  = TB_H + 2 * MAXD;  // 16
constexpr int NT   = 576;  // threads per block (9 waves)

constexpr int Bc = 8, Cc = 64, Hc = 192, Wc = 192;

__global__ __launch_bounds__(NT) void corr_kernel(
    const float* __restrict__ x1, const float* __restrict__ x2,
    float* __restrict__ out)
{
    __shared__ float s_x1[CK][TB_H][TB_W];   // 16 KB
    __shared__ float s_x2[CK][X2H][X2W];     // 40 KB

    const int tid = threadIdx.x;
    const int g   = tid & 63;
    const int di  = tid >> 6;        // 0..8, wave-uniform
    const int gw4 = (g & 7) * 4;     // 0..28
    const int gh  = g >> 3;          // 0..7

    const int w0 = blockIdx.x * TB_W;
    const int h0 = blockIdx.y * TB_H;
    const int b  = blockIdx.z;

    const int HW = Hc * Wc;
    const float* x1b = x1 + (long)b * Cc * HW;
    const float* x2b = x2 + (long)b * Cc * HW;

    float acc[OD][TWp];
#pragma unroll
    for (int dj = 0; dj < OD; ++dj)
#pragma unroll
        for (int p = 0; p < TWp; ++p) acc[dj][p] = 0.f;

    for (int c0 = 0; c0 < Cc; c0 += CK) {
        __syncthreads();  // protect previous chunk's LDS reads

        // ---- stage x1 tile: CK*8*32 = 4096 floats as 1024 float4 (all in-bounds;
        //      tiles divide H,W evenly). Coalesced 16B/lane loads.
        for (int idx = tid; idx < CK * TB_H * TB_W / 4; idx += NT) {
            int f = idx * 4;
            int c = f >> 8;         // / (TB_H*TB_W)
            int r = f & 255;
            int y = r >> 5;         // / TB_W
            int x = r & 31;
            float4 v = *(const float4*)(x1b + (long)(c0 + c) * HW + (h0 + y) * Wc + (w0 + x));
            *(float4*)(&s_x1[c][y][x]) = v;
        }

        // ---- stage x2 halo tile: CK*16*40 = 10240 floats, zero-padded at borders.
        for (int idx = tid; idx < CK * X2H * X2W; idx += NT) {
            int c = idx / (X2H * X2W);
            int r = idx - c * (X2H * X2W);
            int y = r / X2W;
            int x = r - y * X2W;
            int gy = h0 + y - MAXD;
            int gx = w0 + x - MAXD;
            float v = 0.f;
            if ((unsigned)gy < (unsigned)Hc && (unsigned)gx < (unsigned)Wc)
                v = x2b[(long)(c0 + c) * HW + gy * Wc + gx];
            s_x2[c][y][x] = v;
        }
        __syncthreads();

        // ---- compute: per channel, 4x ds_read_b128 -> 36 FMAs
#pragma unroll
        for (int c = 0; c < CK; ++c) {
            float4 a = *(const float4*)(&s_x1[c][gh][gw4]);
            const float* wrow = &s_x2[c][gh + di][gw4];
            float4 b0 = *(const float4*)(wrow);
            float4 b1 = *(const float4*)(wrow + 4);
            float4 b2 = *(const float4*)(wrow + 8);
            float win[12] = {b0.x, b0.y, b0.z, b0.w,
                             b1.x, b1.y, b1.z, b1.w,
                             b2.x, b2.y, b2.z, b2.w};
            float av[4] = {a.x, a.y, a.z, a.w};
#pragma unroll
            for (int dj = 0; dj < OD; ++dj)
#pragma unroll
                for (int p = 0; p < TWp; ++p)
                    acc[dj][p] = fmaf(av[p], win[dj + p], acc[dj][p]);
        }
    }

    // ---- epilogue: 9 float4 stores per thread (mean over C=64)
    const float scale = 1.0f / 64.0f;
    float* ob = out + (((long)b * ND + di * OD) * Hc + (h0 + gh)) * Wc + (w0 + gw4);
#pragma unroll
    for (int dj = 0; dj < OD; ++dj) {
        float4 o;
        o.x = acc[dj][0] * scale;
        o.y = acc[dj][1] * scale;
        o.z = acc[dj][2] * scale;
        o.w = acc[dj][3] * scale;
        *(float4*)(ob + (long)dj * HW) = o;
    }
}

extern "C" void kernel_launch(void* const* d_in, const int* in_sizes, int n_in,
                              void* d_out, int out_size, void* d_ws, size_t ws_size,
                              hipStream_t stream) {
    const float* x1 = (const float*)d_in[0];
    const float* x2 = (const float*)d_in[1];
    float* out = (float*)d_out;
    dim3 grid(Wc / TB_W, Hc / TB_H, Bc);  // (6, 24, 8) = 1152 blocks
    corr_kernel<<<grid, NT, 0, stream>>>(x1, x2, out);
}